// Round 1
// baseline (109.217 us; speedup 1.0000x reference)
//
#include <hip/hip_runtime.h>
#include <math.h>

#define BB 512
#define VV 778
#define FF 1538
#define PP 1024
#define NS 16   // ws slots per batch

// ---------- cone field for one (triangle, 3 points) ----------
__device__ __forceinline__ float cone3(const float3 t[3], const float3 p[3]) {
    const float third = 1.0f / 3.0f;
    float cx = (t[0].x + t[1].x + t[2].x) * third;
    float cy = (t[0].y + t[1].y + t[2].y) * third;
    float cz = (t[0].z + t[1].z + t[2].z) * third;
    float e1x = t[1].x - t[0].x, e1y = t[1].y - t[0].y, e1z = t[1].z - t[0].z;
    float e2x = t[2].x - t[0].x, e2y = t[2].y - t[0].y, e2z = t[2].z - t[0].z;
    float nx = e1y * e2z - e1z * e2y;
    float ny = e1z * e2x - e1x * e2z;
    float nz = e1x * e2y - e1y * e2x;
    float inv = 1.0f / (sqrtf(nx * nx + ny * ny + nz * nz) + 1e-9f);
    nx *= inv; ny *= inv; nz *= inv;
    float s = 0.0f;
#pragma unroll
    for (int i = 0; i < 3; i++) {
        float dx = p[i].x - cx, dy = p[i].y - cy, dz = p[i].z - cz;
        float h = dx * nx + dy * ny + dz * nz;
        float r2 = fmaxf(dx * dx + dy * dy + dz * dz - h * h, 0.0f);
        float rl = fmaxf(-h, 0.0f);
        s += rl * expf(-2.0f * r2);   // 2*sigma^2 = 0.5 -> exp(-rho2/0.5)
    }
    return s;
}

__device__ __forceinline__ void loadTri(const int* __restrict__ faces,
                                        const float* __restrict__ sv,
                                        int f, float3 t[3]) {
    int off = (f >= FF) ? (VV * 3) : 0;   // second hand's verts live at +V
    const int* fp = faces + f * 3;        // faces flat (2F,3)
#pragma unroll
    for (int k = 0; k < 3; k++) {
        int j = fp[k] * 3 + off;
        t[k] = make_float3(sv[j], sv[j + 1], sv[j + 2]);
    }
}

// ---------- kernel A: one block per batch ----------
__global__ __launch_bounds__(256) void per_batch_kernel(
    const float* __restrict__ verts,   // (2,B,V,3)
    const int*   __restrict__ faces,   // (2,F,3)
    const int*   __restrict__ cidx,    // (B,P,2)
    const float* __restrict__ betas,   // (2,B,10)
    const float* __restrict__ transl,  // (2,B,3)
    const float* __restrict__ j3d,     // (2,B,21,3)
    const float* __restrict__ go,      // (2,B,3)
    const float* __restrict__ pose,    // (2,B,45)
    const float* __restrict__ tgt_trans, // (2,B,3)
    const float* __restrict__ tgt_j3d,   // (2,B,21,3)
    const float* __restrict__ tgt_go,    // (2,B,3)
    const float* __restrict__ tgt_pose,  // (2,B,45)
    const float* __restrict__ tgt_shape, // (2,B,10)
    float* __restrict__ ws)            // (B,16)
{
    __shared__ float sv[2 * VV * 3];
    __shared__ float red[4][NS];
    const int b = blockIdx.x, tid = threadIdx.x;

    // stage both hands' vertices for batch b into LDS (coalesced)
    const float* v0 = verts + (size_t)b * VV * 3;
    const float* v1 = verts + (size_t)(BB + b) * VV * 3;
    for (int i = tid; i < VV * 3; i += 256) {
        sv[i] = v0[i];
        sv[VV * 3 + i] = v1[i];
    }
    __syncthreads();

    float part[NS];
#pragma unroll
    for (int k = 0; k < NS; k++) part[k] = 0.0f;

    // collision pairs
    const int2* ci = (const int2*)cidx + (size_t)b * PP;
    for (int p = tid; p < PP; p += 256) {
        int2 fp = ci[p];
        if (fp.x < 0 || fp.y < 0) continue;
        float3 r[3], q[3];
        loadTri(faces, sv, fp.x, r);
        loadTri(faces, sv, fp.y, q);
        part[0] += cone3(r, q) + cone3(q, r);
    }

    // small per-batch loss numerators (raw; masks applied in finalize)
    if (tid < 63) {
        const int t = tid;
        if (t < 10) { float d = betas[b * 10 + t] - betas[(BB + b) * 10 + t]; part[1] = d * d; }
        if (t < 3) {
            float d = (transl[b * 3 + t] - transl[(BB + b) * 3 + t]) -
                      (tgt_trans[b * 3 + t] - tgt_trans[(BB + b) * 3 + t]);
            part[2] = d * d;
        }
        {
            float d = (j3d[b * 63 + t] - j3d[(BB + b) * 63 + t]) -
                      (tgt_j3d[b * 63 + t] - tgt_j3d[(BB + b) * 63 + t]);
            part[3] = d * d;
        }
#pragma unroll
        for (int h = 0; h < 2; h++) {
            const int base = 4 + 6 * h;
            const size_t ob = (size_t)(h * BB + b);
            if (t < 3)  { float d = go[ob * 3 + t] - tgt_go[ob * 3 + t]; part[base + 0] = d * d; }
            if (t < 45) { float d = pose[ob * 45 + t] - tgt_pose[ob * 45 + t]; part[base + 1] = d * d; }
            if (t < 60) {
                int j = 1 + t / 3, c = t % 3;
                float a  = (j3d[ob * 63 + j * 3 + c]     - j3d[ob * 63 + c]) * 1000.0f;
                float b2 = (tgt_j3d[ob * 63 + j * 3 + c] - tgt_j3d[ob * 63 + c]) * 1000.0f;
                part[base + 2] = fabsf(a - b2);
            }
            {
                float a = j3d[ob * 63 + t] * 1000.0f, b2 = tgt_j3d[ob * 63 + t] * 1000.0f;
                part[base + 3] = fabsf(a - b2);
            }
            if (t < 10) { float d = betas[ob * 10 + t] - tgt_shape[ob * 10 + t]; part[base + 4] = d * d; }
            if (t < 3)  { float d = transl[ob * 3 + t] - tgt_trans[ob * 3 + t]; part[base + 5] = fabsf(d); }
        }
    }

    // block reduction: wave shuffle then LDS across the 4 waves
#pragma unroll
    for (int off = 32; off >= 1; off >>= 1) {
#pragma unroll
        for (int k = 0; k < NS; k++) part[k] += __shfl_down(part[k], off);
    }
    const int wave = tid >> 6, lane = tid & 63;
    if (lane == 0) {
#pragma unroll
        for (int k = 0; k < NS; k++) red[wave][k] = part[k];
    }
    __syncthreads();
    if (tid < NS) {
        ws[b * NS + tid] = red[0][tid] + red[1][tid] + red[2][tid] + red[3][tid];
    }
}

// ---------- kernel B: finalize ----------
__global__ __launch_bounds__(256) void finalize_kernel(
    const float* __restrict__ ws,      // (B,16)
    const int*   __restrict__ handed,  // (B,2)
    const int*   __restrict__ validm,  // (2,B)
    const float* __restrict__ logits,  // (B,4)
    const int*   __restrict__ ctgt,    // (B,)
    float* __restrict__ out)           // (12,)
{
    const int tid = threadIdx.x;
    // acc layout: 0 nzsum, 1 nzcnt, 2 shape, 3 transl, 4 j3d, 5 icnt,
    //             6..11 h0 {go,hp,rj,j3,sh,tr}, 12 vcnt0,
    //             13..18 h1 {...}, 19 vcnt1, 20 ce_num, 21 ce_den
    const int NA = 22;
    float acc[22];
#pragma unroll
    for (int k = 0; k < NA; k++) acc[k] = 0.0f;

    for (int b = tid; b < BB; b += 256) {
        const float* w = ws + b * NS;
        float lb = w[0];
        acc[0] += lb;
        acc[1] += (lb != 0.0f) ? 1.0f : 0.0f;
        float inter = ((handed[b * 2] + handed[b * 2 + 1]) == 2) ? 1.0f : 0.0f;
        acc[2] += inter * w[1];
        acc[3] += inter * w[2];
        acc[4] += inter * w[3];
        acc[5] += inter;
#pragma unroll
        for (int h = 0; h < 2; h++) {
            float vm = (float)validm[h * BB + b];
            const int ab = 6 + 7 * h;
#pragma unroll
            for (int k = 0; k < 6; k++) acc[ab + k] += vm * w[4 + 6 * h + k];
            acc[ab + 6] += vm;
        }
        // weighted CE
        float l0 = logits[b * 4 + 0], l1 = logits[b * 4 + 1];
        float l2 = logits[b * 4 + 2], l3 = logits[b * 4 + 3];
        float m = fmaxf(fmaxf(l0, l1), fmaxf(l2, l3));
        float lse = m + logf(expf(l0 - m) + expf(l1 - m) + expf(l2 - m) + expf(l3 - m));
        int t = ctgt[b];
        float lt = (t == 0) ? l0 : (t == 1) ? l1 : (t == 2) ? l2 : l3;
        float nll = lse - lt;
        float cw = (t == 0) ? 1.0f : (t == 3) ? 10.0f : 30.0f;
        float vm = (t != 0) ? 1.0f : 0.0f;
        acc[20] += cw * vm * nll;
        acc[21] += cw * vm;
    }

    // block reduce 22 scalars
#pragma unroll
    for (int off = 32; off >= 1; off >>= 1) {
#pragma unroll
        for (int k = 0; k < NA; k++) acc[k] += __shfl_down(acc[k], off);
    }
    __shared__ float red[4][22];
    const int wave = tid >> 6, lane = tid & 63;
    if (lane == 0) {
#pragma unroll
        for (int k = 0; k < NA; k++) red[wave][k] = acc[k];
    }
    __syncthreads();

    if (tid == 0) {
        float s[22];
#pragma unroll
        for (int k = 0; k < NA; k++)
            s[k] = red[0][k] + red[1][k] + red[2][k] + red[3][k];

        auto idxloss = [](float num, float cnt, float K) -> float {
            float denom = cnt * K;
            return (denom > 0.0f) ? num / fmaxf(denom, 1.0f) : 0.0f;
        };

        out[0] = (s[1] > 0.0f) ? s[0] / fmaxf(s[1], 1.0f) * 100.0f : 0.0f;
        out[1] = idxloss(s[2], s[5], 10.0f);
        out[2] = idxloss(s[3], s[5], 3.0f) * 100.0f;
        out[3] = idxloss(s[4], s[5], 63.0f) * 100.0f;
        out[4] = (idxloss(s[6],  s[12], 3.0f)  + idxloss(s[13], s[19], 3.0f))  * 10.0f;
        out[5] = (idxloss(s[7],  s[12], 45.0f) + idxloss(s[14], s[19], 45.0f)) * 10.0f;
        out[6] = (idxloss(s[8],  s[12], 60.0f) + idxloss(s[15], s[19], 60.0f)) * 0.01f;
        out[7] = (idxloss(s[9],  s[12], 63.0f) + idxloss(s[16], s[19], 63.0f)) * 0.01f;
        out[8] = (idxloss(s[10], s[12], 10.0f) + idxloss(s[17], s[19], 10.0f)) * 10.0f;
        out[9] = (idxloss(s[11], s[12], 3.0f)  + idxloss(s[18], s[19], 3.0f))  * 10.0f;
        out[10] = 0.0f;   // reg: mse(x,x) == 0 identically
        out[11] = s[20] / fmaxf(s[21], 1e-9f);
    }
}

extern "C" void kernel_launch(void* const* d_in, const int* in_sizes, int n_in,
                              void* d_out, int out_size, void* d_ws, size_t ws_size,
                              hipStream_t stream) {
    const float* verts   = (const float*)d_in[0];
    const float* betas   = (const float*)d_in[1];
    const float* transl  = (const float*)d_in[2];
    const float* j3d     = (const float*)d_in[3];
    const float* go      = (const float*)d_in[4];
    const float* pose    = (const float*)d_in[5];
    const float* tt      = (const float*)d_in[6];
    const float* tj      = (const float*)d_in[7];
    const float* tg      = (const float*)d_in[8];
    const float* tp      = (const float*)d_in[9];
    const float* tsh     = (const float*)d_in[10];
    const float* logits  = (const float*)d_in[11];
    const int*   faces   = (const int*)d_in[12];
    const int*   cidx    = (const int*)d_in[13];
    const int*   handed  = (const int*)d_in[14];
    const int*   validm  = (const int*)d_in[15];
    const int*   ctgt    = (const int*)d_in[16];
    float*       ws      = (float*)d_ws;
    float*       out     = (float*)d_out;

    per_batch_kernel<<<BB, 256, 0, stream>>>(verts, faces, cidx, betas, transl,
                                             j3d, go, pose, tt, tj, tg, tp, tsh, ws);
    finalize_kernel<<<1, 256, 0, stream>>>(ws, handed, validm, logits, ctgt, out);
}